// Round 9
// baseline (346.857 us; speedup 1.0000x reference)
//
#include <hip/hip_runtime.h>

typedef unsigned short bf16_t;
typedef short short8 __attribute__((ext_vector_type(8)));
typedef float f32x4 __attribute__((ext_vector_type(4)));
typedef float f32x16 __attribute__((ext_vector_type(16)));
typedef unsigned int u32x4 __attribute__((ext_vector_type(4)));

extern "C" __device__ float __ocml_native_exp2_f32(float);

static __device__ __forceinline__ unsigned short f2bf(float f) {
  unsigned int u = __float_as_uint(f);
  unsigned int r = (u + 0x7FFFu + ((u >> 16) & 1u)) >> 16;
  return (unsigned short)r;
}
static __device__ __forceinline__ float bf2f(unsigned short u) {
  return __uint_as_float((unsigned int)u << 16);
}
static __device__ __forceinline__ unsigned int cvt_pk_bf16(float lo, float hi) {
  unsigned int r;
  asm("v_cvt_pk_bf16_f32 %0, %1, %2" : "=v"(r) : "v"(lo), "v"(hi));
  return r;
}
static __device__ __forceinline__ void pl32swap(unsigned int& a, unsigned int& b) {
  asm("v_permlane32_swap_b32 %0, %1" : "+v"(a), "+v"(b));
}

__device__ __forceinline__ void gload_lds16(const void* g, void* l) {
  __builtin_amdgcn_global_load_lds((const __attribute__((address_space(1))) void*)g,
                                   (__attribute__((address_space(3))) void*)l,
                                   16, 0, 0);
}

// ---------------------------------------------------------------------------
// Fused prep: blocks [0,4096) transpose Wq/Wk/Wv/Wo (1024x1024 each);
// [4096,8192) W1 (1024x4096); [8192,12288) W2 (4096x1024);
// [12288,16384) LayerNorm rows of x; [16384,16640) rope cos/sin table
// ropetbl[s][i] = {cos(s*invfreq_i), sin(s*invfreq_i)} float2, s<2048, i<32.
// ---------------------------------------------------------------------------
__global__ __launch_bounds__(256) void prep_kernel(
    const float* __restrict__ Wq, const float* __restrict__ Wk,
    const float* __restrict__ Wv, const float* __restrict__ Wo,
    const float* __restrict__ W1, const float* __restrict__ W2,
    const float* __restrict__ x, const float* __restrict__ g1,
    const float* __restrict__ be1,
    bf16_t* __restrict__ WqkvT, bf16_t* __restrict__ W1T,
    bf16_t* __restrict__ W2T, bf16_t* __restrict__ xnb,
    float* __restrict__ ropetbl) {
  __shared__ float tile[32][33];
  const int bid = blockIdx.x;
  if (bid < 12288) {
    const float* src;
    bf16_t* dst;
    int rows, cols, bx, by;
    if (bid < 4096) {
      const int z = bid >> 10, r = bid & 1023;
      src = (z == 0) ? Wq : (z == 1) ? Wk : (z == 2) ? Wv : Wo;
      dst = WqkvT + (size_t)z * 1048576;
      rows = 1024; cols = 1024;
      bx = (r & 31) * 32; by = (r >> 5) * 32;
    } else if (bid < 8192) {
      const int r = bid - 4096;
      src = W1; dst = W1T; rows = 1024; cols = 4096;
      bx = (r & 127) * 32; by = (r >> 7) * 32;
    } else {
      const int r = bid - 8192;
      src = W2; dst = W2T; rows = 4096; cols = 1024;
      bx = (r & 31) * 32; by = (r >> 5) * 32;
    }
    const int tx = threadIdx.x & 31, ty = threadIdx.x >> 5;
#pragma unroll
    for (int i = 0; i < 32; i += 8)
      tile[ty + i][tx] = src[(size_t)(by + ty + i) * cols + (bx + tx)];
    __syncthreads();
#pragma unroll
    for (int i = 0; i < 32; i += 8)
      dst[(size_t)(bx + ty + i) * rows + (by + tx)] = f2bf(tile[tx][ty + i]);
  } else if (bid < 16384) {
    const int row = bid - 12288;
    const int tid = threadIdx.x;
    const float4 v = reinterpret_cast<const float4*>(x + (size_t)row * 1024)[tid];
    float s = v.x + v.y + v.z + v.w;
    float ss = v.x * v.x + v.y * v.y + v.z * v.z + v.w * v.w;
#pragma unroll
    for (int off = 32; off; off >>= 1) {
      s += __shfl_xor(s, off, 64);
      ss += __shfl_xor(ss, off, 64);
    }
    float* red = &tile[0][0];
    const int wave = tid >> 6, lane = tid & 63;
    if (lane == 0) { red[wave] = s; red[4 + wave] = ss; }
    __syncthreads();
    const float mu = (red[0] + red[1] + red[2] + red[3]) * (1.f / 1024.f);
    const float ms = (red[4] + red[5] + red[6] + red[7]) * (1.f / 1024.f);
    const float rstd = rsqrtf(ms - mu * mu + 1e-5f);
    const float4 gg = reinterpret_cast<const float4*>(g1)[tid];
    const float4 bb = reinterpret_cast<const float4*>(be1)[tid];
    bf16_t* o = xnb + (size_t)row * 1024 + tid * 4;
    o[0] = f2bf((v.x - mu) * rstd * gg.x + bb.x);
    o[1] = f2bf((v.y - mu) * rstd * gg.y + bb.y);
    o[2] = f2bf((v.z - mu) * rstd * gg.z + bb.z);
    o[3] = f2bf((v.w - mu) * rstd * gg.w + bb.w);
  } else {
    const int id = (bid - 16384) * 256 + threadIdx.x;  // [0, 65536)
    const int s = id >> 5, i = id & 31;
    float sn, cs;
    sincosf((float)s * exp2f((float)i * -0.41524101186f), &sn, &cs);
    reinterpret_cast<float2*>(ropetbl)[id] = make_float2(cs, sn);
  }
}

// ---------------------------------------------------------------------------
// LN2-combine: x2 = sum(4 bf16 partials)+bo+x ; x2 f32 out + xn2 = LN(x2) bf16
// ---------------------------------------------------------------------------
__global__ __launch_bounds__(256) void ln2_combine(const bf16_t* __restrict__ p,
                                                   const float* __restrict__ x,
                                                   const float* __restrict__ bo,
                                                   const float* __restrict__ g,
                                                   const float* __restrict__ be,
                                                   float* __restrict__ x2,
                                                   bf16_t* __restrict__ xn) {
  const int row = blockIdx.x;
  const int tid = threadIdx.x;
  const float4 xv = reinterpret_cast<const float4*>(x + (size_t)row * 1024)[tid];
  const float4 bb = reinterpret_cast<const float4*>(bo)[tid];
  float4 v = {bb.x + xv.x, bb.y + xv.y, bb.z + xv.z, bb.w + xv.w};
#pragma unroll
  for (int z = 0; z < 4; ++z) {
    const ushort4 a = reinterpret_cast<const ushort4*>(p + (size_t)z * 4194304 + (size_t)row * 1024)[tid];
    v.x += bf2f(a.x); v.y += bf2f(a.y); v.z += bf2f(a.z); v.w += bf2f(a.w);
  }
  reinterpret_cast<float4*>(x2 + (size_t)row * 1024)[tid] = v;
  float s = v.x + v.y + v.z + v.w;
  float ss = v.x * v.x + v.y * v.y + v.z * v.z + v.w * v.w;
#pragma unroll
  for (int off = 32; off; off >>= 1) {
    s += __shfl_xor(s, off, 64);
    ss += __shfl_xor(ss, off, 64);
  }
  __shared__ float red[8];
  const int wave = tid >> 6, lane = tid & 63;
  if (lane == 0) { red[wave] = s; red[4 + wave] = ss; }
  __syncthreads();
  const float mu = (red[0] + red[1] + red[2] + red[3]) * (1.f / 1024.f);
  const float ms = (red[4] + red[5] + red[6] + red[7]) * (1.f / 1024.f);
  const float rstd = rsqrtf(ms - mu * mu + 1e-5f);
  const float4 gg = reinterpret_cast<const float4*>(g)[tid];
  const float4 eb = reinterpret_cast<const float4*>(be)[tid];
  bf16_t* o = xn + (size_t)row * 1024 + tid * 4;
  o[0] = f2bf((v.x - mu) * rstd * gg.x + eb.x);
  o[1] = f2bf((v.y - mu) * rstd * gg.y + eb.y);
  o[2] = f2bf((v.z - mu) * rstd * gg.z + eb.z);
  o[3] = f2bf((v.w - mu) * rstd * gg.w + eb.w);
}

// ---------------------------------------------------------------------------
// FFN combine: out = bf(p0)+bf(p1)+bf(p2)+b2+x2
// ---------------------------------------------------------------------------
__global__ __launch_bounds__(256) void ffn_combine(const bf16_t* __restrict__ p0,
                                                   const bf16_t* __restrict__ p2,
                                                   const float* __restrict__ x2,
                                                   const float* __restrict__ b2,
                                                   float* __restrict__ out) {
  const int row = blockIdx.x;
  const int tid = threadIdx.x;
  const ushort4 a0 = reinterpret_cast<const ushort4*>(p0 + (size_t)row * 1024)[tid];
  const ushort4 a1 = reinterpret_cast<const ushort4*>(p0 + 4194304 + (size_t)row * 1024)[tid];
  const ushort4 a2 = reinterpret_cast<const ushort4*>(p2 + (size_t)row * 1024)[tid];
  const float4 xv = reinterpret_cast<const float4*>(x2 + (size_t)row * 1024)[tid];
  const float4 bb = reinterpret_cast<const float4*>(b2)[tid];
  float4 v;
  v.x = bf2f(a0.x) + bf2f(a1.x) + bf2f(a2.x) + bb.x + xv.x;
  v.y = bf2f(a0.y) + bf2f(a1.y) + bf2f(a2.y) + bb.y + xv.y;
  v.z = bf2f(a0.z) + bf2f(a1.z) + bf2f(a2.z) + bb.z + xv.z;
  v.w = bf2f(a0.w) + bf2f(a1.w) + bf2f(a2.w) + bb.w + xv.w;
  reinterpret_cast<float4*>(out + (size_t)row * 1024)[tid] = v;
}

// ---------------------------------------------------------------------------
// attn7: swapped-QK in-register-softmax flash attention (unchanged from R6).
// ---------------------------------------------------------------------------
__global__ __launch_bounds__(256, 2) void attn7(const bf16_t* __restrict__ qb,
                                                const bf16_t* __restrict__ kb,
                                                const bf16_t* __restrict__ vt,
                                                bf16_t* __restrict__ out) {
  const int bh = blockIdx.x;
  const int tid = threadIdx.x, wave = tid >> 6, lane = tid & 63;
  const int l31 = lane & 31, hi = lane >> 5;
  const int q0 = blockIdx.y * 128 + wave * 32;
  const size_t kvb = (size_t)bh * (2048 * 64);

  __shared__ __align__(16) bf16_t Ks[2][2][4096];
  __shared__ __align__(16) bf16_t Vs[2][2][4096];

  short8 qf[4];
#pragma unroll
  for (int st = 0; st < 4; ++st)
    qf[st] = *(const short8*)&qb[kvb + (size_t)(q0 + l31) * 64 + st * 16 + hi * 8];

  int kidx[2][4];
  int vidx[2][2][2];
#pragma unroll
  for (int st = 0; st < 4; ++st) {
    const int R0 = l31, R1 = 32 + l31;
    kidx[0][st] = (R0 * 8 + (((st << 1) | hi) ^ (R0 & 7))) * 8;
    kidx[1][st] = (R1 * 8 + (((st << 1) | hi) ^ (R1 & 7))) * 8;
  }
#pragma unroll
  for (int f = 0; f < 2; ++f)
#pragma unroll
    for (int ks = 0; ks < 2; ++ks) {
      const int R0 = l31, R1 = 32 + l31;
      vidx[0][f][ks] = (R0 * 8 + (((f << 2) | (ks << 1) | hi) ^ (R0 & 7))) * 8;
      vidx[1][f][ks] = (R1 * 8 + (((f << 2) | (ks << 1) | hi) ^ (R1 & 7))) * 8;
    }

  short8 vones;
#pragma unroll
  for (int j = 0; j < 8; ++j) vones[j] = (short)0x3F80;

  f32x16 acc0 = {}, acc1 = {}, lacc = {};
  const f32x16 fz = {};

#define STAGE(DST, T0)                                                                     \
  {                                                                                        \
    _Pragma("unroll") for (int sub = 0; sub < 2; ++sub) {                                  \
      _Pragma("unroll") for (int j = 0; j < 2; ++j) {                                      \
        const int s = wave * 128 + j * 64 + lane;                                          \
        const int r = s >> 3;                                                              \
        const int c = (s & 7) ^ (r & 7);                                                   \
        gload_lds16(kb + kvb + (size_t)((T0) + sub * 64 + r) * 64 + c * 8,                 \
                    &Ks[DST][sub][(size_t)s * 8]);                                         \
        gload_lds16(vt + kvb + (size_t)r * 2048 + (T0) + sub * 64 + c * 8,                 \
                    &Vs[DST][sub][(size_t)s * 8]);                                         \
      }                                                                                    \
    }                                                                                      \
  }

#define QK(BUF, SUB, P0, P1)                                                               \
  {                                                                                        \
    short8 kfa[4], kfb[4];                                                                 \
    _Pragma("unroll") for (int st = 0; st < 4; ++st) {                                     \
      kfa[st] = *(const short8*)&Ks[BUF][SUB][kidx[0][st]];                                \
      kfb[st] = *(const short8*)&Ks[BUF][SUB][kidx[1][st]];                                \
    }                                                                                      \
    __builtin_amdgcn_s_setprio(1);                                                         \
    P0 = __builtin_amdgcn_mfma_f32_32x32x16_bf16(kfa[0], qf[0], fz, 0, 0, 0);              \
    P1 = __builtin_amdgcn_mfma_f32_32x32x16_bf16(kfb[0], qf[0], fz, 0, 0, 0);              \
    _Pragma("unroll") for (int st = 1; st < 4; ++st) {                                     \
      P0 = __builtin_amdgcn_mfma_f32_32x32x16_bf16(kfa[st], qf[st], P0, 0, 0, 0);          \
      P1 = __builtin_amdgcn_mfma_f32_32x32x16_bf16(kfb[st], qf[st], P1, 0, 0, 0);          \
    }                                                                                      \
    __builtin_amdgcn_s_setprio(0);                                                         \
  }

#define SMPV(BUF, SUB, P0, P1)                                                             \
  {                                                                                        \
    _Pragma("unroll") for (int f = 0; f < 2; ++f) {                                        \
      f32x16& p = f ? P1 : P0;                                                             \
      float e[16];                                                                         \
      _Pragma("unroll") for (int r = 0; r < 16; ++r) e[r] = __ocml_native_exp2_f32(p[r]);  \
      unsigned int a0 = cvt_pk_bf16(e[0], e[1]), b0 = cvt_pk_bf16(e[4], e[5]);             \
      unsigned int a1 = cvt_pk_bf16(e[2], e[3]), b1 = cvt_pk_bf16(e[6], e[7]);             \
      unsigned int a2 = cvt_pk_bf16(e[8], e[9]), b2 = cvt_pk_bf16(e[12], e[13]);           \
      unsigned int a3 = cvt_pk_bf16(e[10], e[11]), b3 = cvt_pk_bf16(e[14], e[15]);         \
      pl32swap(a0, b0);                                                                    \
      pl32swap(a1, b1);                                                                    \
      pl32swap(a2, b2);                                                                    \
      pl32swap(a3, b3);                                                                    \
      const u32x4 w0 = {a0, a1, b0, b1};                                                   \
      const u32x4 w1 = {a2, a3, b2, b3};                                                   \
      const short8 pf0 = __builtin_bit_cast(short8, w0);                                   \
      const short8 pf1 = __builtin_bit_cast(short8, w1);                                   \
      const short8 vf00 = *(const short8*)&Vs[BUF][SUB][vidx[0][f][0]];                    \
      const short8 vf10 = *(const short8*)&Vs[BUF][SUB][vidx[1][f][0]];                    \
      const short8 vf01 = *(const short8*)&Vs[BUF][SUB][vidx[0][f][1]];                    \
      const short8 vf11 = *(const short8*)&Vs[BUF][SUB][vidx[1][f][1]];                    \
      __builtin_amdgcn_s_setprio(1);                                                       \
      lacc = __builtin_amdgcn_mfma_f32_32x32x16_bf16(pf0, vones, lacc, 0, 0, 0);           \
      acc0 = __builtin_amdgcn_mfma_f32_32x32x16_bf16(pf0, vf00, acc0, 0, 0, 0);            \
      acc1 = __builtin_amdgcn_mfma_f32_32x32x16_bf16(pf0, vf10, acc1, 0, 0, 0);            \
      lacc = __builtin_amdgcn_mfma_f32_32x32x16_bf16(pf1, vones, lacc, 0, 0, 0);           \
      acc0 = __builtin_amdgcn_mfma_f32_32x32x16_bf16(pf1, vf01, acc0, 0, 0, 0);            \
      acc1 = __builtin_amdgcn_mfma_f32_32x32x16_bf16(pf1, vf11, acc1, 0, 0, 0);            \
      __builtin_amdgcn_s_setprio(0);                                                       \
    }                                                                                      \
  }

#define CITER(BUF, NT0, DOPREF)                                                            \
  {                                                                                        \
    if (DOPREF) {                                                                          \
      STAGE((BUF) ^ 1, NT0);                                                               \
      asm volatile("s_waitcnt vmcnt(8)" ::: "memory");                                     \
    } else {                                                                               \
      asm volatile("s_waitcnt vmcnt(0)" ::: "memory");                                     \
    }                                                                                      \
    __builtin_amdgcn_s_barrier();                                                          \
    asm volatile("" ::: "memory");                                                         \
    f32x16 pa0, pa1, pb0, pb1;                                                             \
    QK(BUF, 0, pa0, pa1);                                                                  \
    QK(BUF, 1, pb0, pb1);                                                                  \
    SMPV(BUF, 0, pa0, pa1);                                                                \
    SMPV(BUF, 1, pb0, pb1);                                                                \
    asm volatile("" ::: "memory");                                                         \
    __builtin_amdgcn_s_barrier();                                                          \
    asm volatile("" ::: "memory");                                                         \
  }

  STAGE(0, 0);

  for (int k = 0; k < 7; ++k) {
    CITER(0, (2 * k + 1) * 128, 1)
    CITER(1, (2 * k + 2) * 128, 1)
  }
  CITER(0, 1920, 1)
  CITER(1, 0, 0)
#undef CITER
#undef SMPV
#undef QK
#undef STAGE

  const int b = bh >> 4, h = bh & 15;
#pragma unroll
  for (int r = 0; r < 16; ++r) {
    const int qrow = (r & 3) + 8 * (r >> 2) + 4 * hi;
    const float rl = 1.f / lacc[r];
    const size_t ro = (size_t)(b * 2048 + q0 + qrow) * 1024 + h * 64;
    out[ro + l31] = f2bf(acc0[r] * rl);
    out[ro + 32 + l31] = f2bf(acc1[r] * rl);
  }
}

// ---------------------------------------------------------------------------
// gemm_ff1_256: 256x256-tile 8-wave 8-phase counted-vmcnt bf16 GEMM for FF1
// (unchanged from R6).
// ---------------------------------------------------------------------------
#define SWZ4(r) (((r) ^ ((r) >> 2)) & 3)
#define HP(SL, H) (dynlds + (size_t)(((SL) * 4 + (H)) * 8192))

#define STAGE8(dst, src, row0, kc0)                                             \
  {                                                                             \
    _Pragma("unroll") for (int j = 0; j < 2; ++j) {                             \
      const int s_ = j * 512 + tid;                                             \
      const int r_ = s_ >> 2;                                                   \
      const int c_ = (s_ & 3) ^ SWZ4(r_);                                       \
      gload_lds16(src + (size_t)((row0) + r_) * 1024 + (kc0) + c_ * 8,          \
                  (dst) + (size_t)s_ * 8);                                      \
    }                                                                           \
  }

#define PHASE(SL, KH, MH, STG, VMW)                                             \
  {                                                                             \
    STG;                                                                        \
    short8 af_[4];                                                              \
    _Pragma("unroll") for (int q4 = 0; q4 < 4; ++q4)                            \
      af_[q4] = *(const short8*)(HP(SL, KH) + aidx[(MH) * 4 + q4]);             \
    if ((MH) == 0) {                                                            \
      _Pragma("unroll") for (int ni = 0; ni < 4; ++ni)                          \
        bfr[ni] = *(const short8*)(HP(SL, 2 + (KH)) + bidx[ni]);                \
    }                                                                           \
    VMW;                                                                        \
    asm volatile("" ::: "memory");                                              \
    __builtin_amdgcn_s_barrier();                                               \
    asm volatile("" ::: "memory");                                              \
    __builtin_amdgcn_s_setprio(1);                                              \
    _Pragma("unroll") for (int q4 = 0; q4 < 4; ++q4)                            \
      _Pragma("unroll") for (int ni = 0; ni < 4; ++ni)                          \
        acc[(MH) * 4 + q4][ni] = __builtin_amdgcn_mfma_f32_16x16x32_bf16(       \
            af_[q4], bfr[ni], acc[(MH) * 4 + q4][ni], 0, 0, 0);                 \
    __builtin_amdgcn_s_setprio(0);                                              \
    asm volatile("" ::: "memory");                                              \
    __builtin_amdgcn_s_barrier();                                               \
    asm volatile("" ::: "memory");                                              \
  }

#define KTILE(SL, KT, VM2, VM4)                                                 \
  PHASE(SL, 0, 0,                                                               \
        if ((KT) + 1 < 16) STAGE8(HP((SL) ^ 1, 2), BT, n0, ((KT) + 1) * 64),    \
        (void)0)                                                                \
  PHASE(SL, 0, 1,                                                               \
        if ((KT) + 1 < 16) STAGE8(HP((SL) ^ 1, 1), A, m0, ((KT) + 1) * 64 + 32),\
        asm volatile("s_waitcnt vmcnt(" #VM2 ")" ::: "memory"))                 \
  PHASE(SL, 1, 0,                                                               \
        if ((KT) + 1 < 16) STAGE8(HP((SL) ^ 1, 3), BT, n0, ((KT) + 1) * 64 + 32),\
        (void)0)                                                                \
  PHASE(SL, 1, 1,                                                               \
        if ((KT) + 2 < 16) STAGE8(HP(SL, 0), A, m0, ((KT) + 2) * 64),           \
        asm volatile("s_waitcnt vmcnt(" #VM4 ")" ::: "memory"))

__global__ __launch_bounds__(512, 2) void gemm_ff1_256(
    const bf16_t* __restrict__ A, const bf16_t* __restrict__ BT,
    const float* __restrict__ bias, bf16_t* __restrict__ ob) {
  extern __shared__ bf16_t dynlds[];
  const int tid = threadIdx.x;
  const int wave = tid >> 6, lane = tid & 63;
  const int row16 = lane & 15, quad = lane >> 4;
  const int wr = wave >> 2, wc = wave & 3;
  const int m0 = blockIdx.x * 256, n0 = blockIdx.y * 256;

  int aidx[8], bidx[4];
#pragma unroll
  for (int mi = 0; mi < 8; ++mi) {
    const int R = wr * 128 + mi * 16 + row16;
    aidx[mi] = R * 32 + (quad ^ SWZ4(R)) * 8;
  }
#pragma unroll
  for (int ni = 0; ni < 4; ++ni) {
    const int R = wc * 64 + ni * 16 + row16;
    bidx[ni] = R * 32 + (quad ^ SWZ4(R)) * 8;
  }

  f32x4 acc[8][4];
#pragma unroll
  for (int i = 0; i < 8; ++i)
#pragma unroll
    for (int j = 0; j < 4; ++j) acc[i][j] = (f32x4){0.f, 0.f, 0.f, 0.f};
  short8 bfr[4];

  STAGE8(HP(0, 0), A, m0, 0);
  STAGE8(HP(0, 2), BT, n0, 0);
  STAGE8(HP(0, 1), A, m0, 32);
  STAGE8(HP(0, 3), BT, n0, 32);
  STAGE8(HP(1, 0), A, m0, 64);
  __syncthreads();

  for (int kt2 = 0; kt2 < 7; ++kt2) {
    const int kt = 2 * kt2;
    KTILE(0, kt, 6, 4)
    KTILE(1, kt + 1, 6, 4)
  }
  KTILE(0, 14, 6, 4)
  KTILE(1, 15, 0, 0)

  __syncthreads();
  bf16_t* ct = dynlds;  // [128][264]
  float bsv[4];
#pragma unroll
  for (int ni = 0; ni < 4; ++ni) bsv[ni] = bias[n0 + wc * 64 + ni * 16 + row16];
#pragma unroll
  for (int mh = 0; mh < 2; ++mh) {
    if (wr == mh) {
#pragma unroll
      for (int mi = 0; mi < 8; ++mi)
#pragma unroll
        for (int ni = 0; ni < 4; ++ni)
#pragma unroll
          for (int r = 0; r < 4; ++r) {
            const float c = fmaxf(acc[mi][ni][r] + bsv[ni], 0.f);
            ct[(size_t)(mi * 16 + quad * 4 + r) * 264 + wc * 64 + ni * 16 + row16] = f2bf(c);
          }
    }
    __syncthreads();
#pragma unroll
    for (int it = 0; it < 8; ++it) {
      const int u = it * 512 + tid;
      const int lr = u >> 5, lcq = u & 31;
      const uint4 v = *(const uint4*)&ct[(size_t)lr * 264 + lcq * 8];
      *(uint4*)&ob[(size_t)(m0 + mh * 128 + lr) * 4096 + n0 + lcq * 8] = v;
    }
    __syncthreads();
  }
}

// ---------------------------------------------------------------------------
// bf16 MFMA GEMM, C = A[M][K] @ BT[N][K]^T (m97-class; QKV/Wo/FF2).
// MODE_QKV epilogue fuses RoPE (Q scaled by 0.125*log2e) and writes V
// transposed directly to vt[b,h,d,s] — rope_bf16 and vtrans kernels deleted.
// ---------------------------------------------------------------------------
enum { MODE_QKV = 0, MODE_FF1 = 1, MODE_PART = 2 };

template <int MODE>
__global__ __launch_bounds__(256) void gemm_bt(
    const bf16_t* __restrict__ A, const bf16_t* __restrict__ BT,
    int M, int N, int K, int kspan,
    const float* __restrict__ bias0, const float* __restrict__ bias1,
    const float* __restrict__ bias2, const float* __restrict__ ropetbl,
    bf16_t* __restrict__ ob0, bf16_t* __restrict__ ob1, bf16_t* __restrict__ ob2) {
  __shared__ __align__(16) char smem[34816];
  bf16_t* As = (bf16_t*)smem;
  bf16_t* Bs = (bf16_t*)(smem + 16384);
  const int tid = threadIdx.x;
  const int wave = tid >> 6, lane = tid & 63;
  const int row16 = lane & 15, quad = lane >> 4;
  const int m0 = blockIdx.x * 128, n0 = blockIdx.y * 128;
  const int wm = (wave & 1) << 6, wn = (wave >> 1) << 6;

  f32x4 acc[4][4];
#pragma unroll
  for (int i = 0; i < 4; ++i)
#pragma unroll
    for (int j = 0; j < 4; ++j) acc[i][j] = (f32x4){0.f, 0.f, 0.f, 0.f};

  const int kb = blockIdx.z * kspan;
  const int kend = (kb + kspan < K) ? kb + kspan : K;

  for (int k0 = kb; k0 < kend; k0 += 64) {
#pragma unroll
    for (int j = 0; j < 4; ++j) {
      const int s = j * 256 + tid;
      const int r = s >> 3;
      const int cg = ((s & 7) ^ (r & 7)) << 3;
      gload_lds16(A + (size_t)(m0 + r) * K + k0 + cg, As + (size_t)s * 8);
      gload_lds16(BT + (size_t)(n0 + r) * K + k0 + cg, Bs + (size_t)s * 8);
    }
    __syncthreads();
    const int sw = row16 & 7;
#pragma unroll
    for (int kk = 0; kk < 2; ++kk) {
      short8 af[4], bfr[4];
#pragma unroll
      for (int mi = 0; mi < 4; ++mi)
        af[mi] = *(const short8*)&As[(size_t)(wm + mi * 16 + row16) * 64 + (((kk << 2) | quad) ^ sw) * 8];
#pragma unroll
      for (int ni = 0; ni < 4; ++ni)
        bfr[ni] = *(const short8*)&Bs[(size_t)(wn + ni * 16 + row16) * 64 + (((kk << 2) | quad) ^ sw) * 8];
#pragma unroll
      for (int mi = 0; mi < 4; ++mi)
#pragma unroll
        for (int ni = 0; ni < 4; ++ni)
          acc[mi][ni] =
              __builtin_amdgcn_mfma_f32_16x16x32_bf16(af[mi], bfr[ni], acc[mi][ni], 0, 0, 0);
    }
    __syncthreads();
  }

  bf16_t* ct = (bf16_t*)smem;  // [128][136]
#pragma unroll
  for (int mi = 0; mi < 4; ++mi)
#pragma unroll
    for (int ni = 0; ni < 4; ++ni) {
      const int gn = n0 + wn + ni * 16 + row16;
      float bsv = 0.f;
      if (MODE == MODE_QKV)
        bsv = (gn < 1024) ? bias0[gn] : (gn < 2048) ? bias1[gn - 1024] : bias2[gn - 2048];
      else if (MODE == MODE_FF1)
        bsv = bias0[gn];
#pragma unroll
      for (int r = 0; r < 4; ++r) {
        float c = acc[mi][ni][r] + bsv;
        if (MODE == MODE_FF1) c = fmaxf(c, 0.f);
        ct[(size_t)(wm + mi * 16 + quad * 4 + r) * 136 + wn + ni * 16 + row16] = f2bf(c);
      }
    }
  __syncthreads();

  if (MODE == MODE_QKV && n0 >= 2048) {
    // V: transposed store to vt[b,h,d,2048]
    const int b = m0 >> 11, sb = m0 & 2047;
#pragma unroll
    for (int it = 0; it < 8; ++it) {
      const int u = it * 256 + tid;
      const int sg = u & 15, dcol = u >> 4;  // dcol in [0,128)
      const int nnv = (n0 - 2048) + dcol;
      const int h = nnv >> 6, dd = nnv & 63;
      unsigned short eb[8];
#pragma unroll
      for (int k = 0; k < 8; ++k) {
        const int kk = (k + sg) & 7;  // stagger: breaks LDS bank conflicts
        eb[kk] = ct[(size_t)(sg * 8 + kk) * 136 + dcol];
      }
      uint4 o;
      o.x = (unsigned)eb[0] | ((unsigned)eb[1] << 16);
      o.y = (unsigned)eb[2] | ((unsigned)eb[3] << 16);
      o.z = (unsigned)eb[4] | ((unsigned)eb[5] << 16);
      o.w = (unsigned)eb[6] | ((unsigned)eb[7] << 16);
      *(uint4*)&ob2[(((size_t)b * 16 + h) * 64 + dd) * 2048 + sb + sg * 8] = o;
    }
    return;
  }

  const int lr0 = tid >> 4, lc = tid & 15;
#pragma unroll
  for (int i = 0; i < 8; ++i) {
    const int lr = i * 16 + lr0;
    const uint4 v = *(const uint4*)&ct[(size_t)lr * 136 + lc * 8];
    const int gm = m0 + lr;
    if (MODE == MODE_QKV) {
      // Q or K: fused RoPE on adjacent pairs, then [b,h,s,d] store.
      const int nn = (n0 & 1023) + lc * 8;
      const int h = nn >> 6, d0 = nn & 63;
      const int i0 = d0 >> 1;  // pair index base (multiple of 4)
      const int b = gm >> 11, s = gm & 2047;
      const float scale = (n0 < 1024) ? 0.18033688f : 1.0f;  // 0.125*log2(e)
      const float4 t0 = *(const float4*)&ropetbl[((size_t)s * 32 + i0) * 2];
      const float4 t1 = *(const float4*)&ropetbl[((size_t)s * 32 + i0) * 2 + 4];
      const float e0 = bf2f(v.x & 0xffff), e1 = bf2f(v.x >> 16);
      const float e2 = bf2f(v.y & 0xffff), e3 = bf2f(v.y >> 16);
      const float e4 = bf2f(v.z & 0xffff), e5 = bf2f(v.z >> 16);
      const float e6 = bf2f(v.w & 0xffff), e7 = bf2f(v.w >> 16);
      uint4 o;
      o.x = (unsigned)f2bf((e0 * t0.x - e1 * t0.y) * scale) |
            ((unsigned)f2bf((e0 * t0.y + e1 * t0.x) * scale) << 16);
      o.y = (unsigned)f2bf((e2 * t0.z - e3 * t0.w) * scale) |
            ((unsigned)f2bf((e2 * t0.w + e3 * t0.z) * scale) << 16);
      o.z = (unsigned)f2bf((e4 * t1.x - e5 * t1.y) * scale) |
            ((unsigned)f2bf((e4 * t1.y + e5 * t1.x) * scale) << 16);
      o.w = (unsigned)f2bf((e6 * t1.z - e7 * t1.w) * scale) |
            ((unsigned)f2bf((e6 * t1.w + e7 * t1.z) * scale) << 16);
      bf16_t* dst = (n0 < 1024) ? ob0 : ob1;
      *(uint4*)&dst[(((size_t)b * 16 + h) * 2048 + s) * 64 + d0] = o;
    } else if (MODE == MODE_FF1) {
      *(uint4*)&ob0[(size_t)gm * N + n0 + lc * 8] = v;
    } else {
      bf16_t* dst = (blockIdx.z == 2) ? ob1 : ob0 + (size_t)blockIdx.z * 4194304;
      *(uint4*)&dst[(size_t)gm * N + n0 + lc * 8] = v;
    }
  }
}

// ---------------------------------------------------------------------------
extern "C" void kernel_launch(void* const* d_in, const int* in_sizes, int n_in,
                              void* d_out, int out_size, void* d_ws, size_t ws_size,
                              hipStream_t stream) {
  const float* x = (const float*)d_in[0];
  const float* Wq = (const float*)d_in[1];
  const float* bq = (const float*)d_in[2];
  const float* Wk = (const float*)d_in[3];
  const float* bk = (const float*)d_in[4];
  const float* Wv = (const float*)d_in[5];
  const float* bv = (const float*)d_in[6];
  const float* Wo = (const float*)d_in[7];
  const float* bo = (const float*)d_in[8];
  const float* W1 = (const float*)d_in[9];
  const float* b1 = (const float*)d_in[10];
  const float* W2 = (const float*)d_in[11];
  const float* b2 = (const float*)d_in[12];
  const float* g1 = (const float*)d_in[13];
  const float* be1 = (const float*)d_in[14];
  const float* g2 = (const float*)d_in[15];
  const float* be2 = (const float*)d_in[16];
  float* out = (float*)d_out;

  char* ws = (char*)d_ws;
  size_t off = 0;
  auto alloc = [&](size_t bytes) {
    void* p = ws + off;
    off += (bytes + 255) & ~(size_t)255;
    return p;
  };
  bf16_t* WqkvT = (bf16_t*)alloc(3072ULL * 1024 * 2);  // [0,6MB)
  bf16_t* WoT = (bf16_t*)alloc(1024ULL * 1024 * 2);    // [6,8)
  bf16_t* W1T = (bf16_t*)alloc(4096ULL * 1024 * 2);    // [8,16)
  bf16_t* W2T = (bf16_t*)alloc(1024ULL * 4096 * 2);    // [16,24)
  bf16_t* xnb = (bf16_t*)alloc(4096ULL * 1024 * 2);    // [24,32)
  bf16_t* qb = (bf16_t*)alloc(4194304ULL * 2);         // [32,40)
  bf16_t* kb = (bf16_t*)alloc(4194304ULL * 2);         // [40,48)
  bf16_t* vraw = (bf16_t*)alloc(4194304ULL * 2);       // [48,56) now: rope table (dead after QKV)
  bf16_t* vt = (bf16_t*)alloc(4194304ULL * 2);         // [56,64)
  bf16_t* h1 = qb;       // FF1 out [4096][4096] bf16 over [32,64)
  bf16_t* x2p = qb;      // X2 bf16 partials (4 x 8MB) over [32,64), pre-FF1
  bf16_t* ffp = WqkvT;   // FF2 partials 0,1 over dead weights [0,16)
  float* x2 = (float*)alloc(16777216ULL);              // [64,80)
  float* ropetbl = (float*)vraw;                       // 512KB within [48,56)

  static bool attrset = false;
  if (!attrset) {
    hipFuncSetAttribute((const void*)gemm_ff1_256,
                        hipFuncAttributeMaxDynamicSharedMemorySize, 131072);
    attrset = true;
  }

  prep_kernel<<<16640, 256, 0, stream>>>(Wq, Wk, Wv, Wo, W1, W2, x, g1, be1,
                                         WqkvT, W1T, W2T, xnb, ropetbl);

  // QKV with fused RoPE (Q,K) + transposed V store (vt) in the epilogue.
  gemm_bt<MODE_QKV><<<dim3(32, 24, 1), 256, 0, stream>>>(xnb, WqkvT, 4096, 3072, 1024, 1024,
                                                         bq, bk, bv, ropetbl, qb, kb, vt);

  attn7<<<dim3(32, 16), 256, 0, stream>>>(qb, kb, vt, xnb);

  // X2 = attn_out @ Wo, split-K=4 (kspan 256)
  gemm_bt<MODE_PART><<<dim3(32, 8, 4), 256, 0, stream>>>(xnb, WoT, 4096, 1024, 1024, 256,
                                                         nullptr, nullptr, nullptr, nullptr,
                                                         x2p, x2p + 2 * 4194304, nullptr);

  ln2_combine<<<4096, 256, 0, stream>>>(x2p, x, bo, g2, be2, x2, xnb);

  // FF1 via 8-phase 256^2 kernel
  gemm_ff1_256<<<dim3(16, 16), 512, 131072, stream>>>(xnb, W1T, b1, h1);

  // FF2 = h1 @ W2, split-K=3 (1408/1408/1280)
  gemm_bt<MODE_PART><<<dim3(32, 8, 3), 256, 0, stream>>>(h1, W2T, 4096, 1024, 4096, 1408,
                                                         nullptr, nullptr, nullptr, nullptr,
                                                         ffp, xnb, nullptr);

  ffn_combine<<<4096, 256, 0, stream>>>(ffp, xnb, x2, b2, out);
}

// Round 11
// 338.267 us; speedup vs baseline: 1.0254x; 1.0254x over previous
//
#include <hip/hip_runtime.h>

typedef unsigned short bf16_t;
typedef short short8 __attribute__((ext_vector_type(8)));
typedef float f32x4 __attribute__((ext_vector_type(4)));
typedef float f32x16 __attribute__((ext_vector_type(16)));
typedef unsigned int u32x4 __attribute__((ext_vector_type(4)));

extern "C" __device__ float __ocml_native_exp2_f32(float);

static __device__ __forceinline__ unsigned short f2bf(float f) {
  unsigned int u = __float_as_uint(f);
  unsigned int r = (u + 0x7FFFu + ((u >> 16) & 1u)) >> 16;
  return (unsigned short)r;
}
static __device__ __forceinline__ float bf2f(unsigned short u) {
  return __uint_as_float((unsigned int)u << 16);
}
static __device__ __forceinline__ unsigned int cvt_pk_bf16(float lo, float hi) {
  unsigned int r;
  asm("v_cvt_pk_bf16_f32 %0, %1, %2" : "=v"(r) : "v"(lo), "v"(hi));
  return r;
}
static __device__ __forceinline__ void pl32swap(unsigned int& a, unsigned int& b) {
  asm("v_permlane32_swap_b32 %0, %1" : "+v"(a), "+v"(b));
}

__device__ __forceinline__ void gload_lds16(const void* g, void* l) {
  __builtin_amdgcn_global_load_lds((const __attribute__((address_space(1))) void*)g,
                                   (__attribute__((address_space(3))) void*)l,
                                   16, 0, 0);
}

// ---------------------------------------------------------------------------
// Fused prep: blocks [0,4096) transpose Wq/Wk/Wv/Wo (1024x1024 each);
// [4096,8192) W1 (1024x4096); [8192,12288) W2 (4096x1024);
// [12288,16384) LayerNorm rows of x; [16384,16640) packed rope table
// ropetbl[s][i] = bf16(cos)|bf16(sin)<<16 (u32), s<2048, i<32 (256 KB).
// ---------------------------------------------------------------------------
__global__ __launch_bounds__(256) void prep_kernel(
    const float* __restrict__ Wq, const float* __restrict__ Wk,
    const float* __restrict__ Wv, const float* __restrict__ Wo,
    const float* __restrict__ W1, const float* __restrict__ W2,
    const float* __restrict__ x, const float* __restrict__ g1,
    const float* __restrict__ be1,
    bf16_t* __restrict__ WqkvT, bf16_t* __restrict__ W1T,
    bf16_t* __restrict__ W2T, bf16_t* __restrict__ xnb,
    unsigned int* __restrict__ ropetbl) {
  __shared__ float tile[32][33];
  const int bid = blockIdx.x;
  if (bid < 12288) {
    const float* src;
    bf16_t* dst;
    int rows, cols, bx, by;
    if (bid < 4096) {
      const int z = bid >> 10, r = bid & 1023;
      src = (z == 0) ? Wq : (z == 1) ? Wk : (z == 2) ? Wv : Wo;
      dst = WqkvT + (size_t)z * 1048576;
      rows = 1024; cols = 1024;
      bx = (r & 31) * 32; by = (r >> 5) * 32;
    } else if (bid < 8192) {
      const int r = bid - 4096;
      src = W1; dst = W1T; rows = 1024; cols = 4096;
      bx = (r & 127) * 32; by = (r >> 7) * 32;
    } else {
      const int r = bid - 8192;
      src = W2; dst = W2T; rows = 4096; cols = 1024;
      bx = (r & 31) * 32; by = (r >> 5) * 32;
    }
    const int tx = threadIdx.x & 31, ty = threadIdx.x >> 5;
#pragma unroll
    for (int i = 0; i < 32; i += 8)
      tile[ty + i][tx] = src[(size_t)(by + ty + i) * cols + (bx + tx)];
    __syncthreads();
#pragma unroll
    for (int i = 0; i < 32; i += 8)
      dst[(size_t)(bx + ty + i) * rows + (by + tx)] = f2bf(tile[tx][ty + i]);
  } else if (bid < 16384) {
    const int row = bid - 12288;
    const int tid = threadIdx.x;
    const float4 v = reinterpret_cast<const float4*>(x + (size_t)row * 1024)[tid];
    float s = v.x + v.y + v.z + v.w;
    float ss = v.x * v.x + v.y * v.y + v.z * v.z + v.w * v.w;
#pragma unroll
    for (int off = 32; off; off >>= 1) {
      s += __shfl_xor(s, off, 64);
      ss += __shfl_xor(ss, off, 64);
    }
    float* red = &tile[0][0];
    const int wave = tid >> 6, lane = tid & 63;
    if (lane == 0) { red[wave] = s; red[4 + wave] = ss; }
    __syncthreads();
    const float mu = (red[0] + red[1] + red[2] + red[3]) * (1.f / 1024.f);
    const float ms = (red[4] + red[5] + red[6] + red[7]) * (1.f / 1024.f);
    const float rstd = rsqrtf(ms - mu * mu + 1e-5f);
    const float4 gg = reinterpret_cast<const float4*>(g1)[tid];
    const float4 bb = reinterpret_cast<const float4*>(be1)[tid];
    bf16_t* o = xnb + (size_t)row * 1024 + tid * 4;
    o[0] = f2bf((v.x - mu) * rstd * gg.x + bb.x);
    o[1] = f2bf((v.y - mu) * rstd * gg.y + bb.y);
    o[2] = f2bf((v.z - mu) * rstd * gg.z + bb.z);
    o[3] = f2bf((v.w - mu) * rstd * gg.w + bb.w);
  } else {
    const int id = (bid - 16384) * 256 + threadIdx.x;  // [0, 65536)
    const int s = id >> 5, i = id & 31;
    float sn, cs;
    sincosf((float)s * exp2f((float)i * -0.41524101186f), &sn, &cs);
    ropetbl[id] = (unsigned int)f2bf(cs) | ((unsigned int)f2bf(sn) << 16);
  }
}

// ---------------------------------------------------------------------------
// LN2-combine: x2 = sum(4 bf16 partials)+bo+x ; x2 f32 out + xn2 = LN(x2) bf16
// ---------------------------------------------------------------------------
__global__ __launch_bounds__(256) void ln2_combine(const bf16_t* __restrict__ p,
                                                   const float* __restrict__ x,
                                                   const float* __restrict__ bo,
                                                   const float* __restrict__ g,
                                                   const float* __restrict__ be,
                                                   float* __restrict__ x2,
                                                   bf16_t* __restrict__ xn) {
  const int row = blockIdx.x;
  const int tid = threadIdx.x;
  const float4 xv = reinterpret_cast<const float4*>(x + (size_t)row * 1024)[tid];
  const float4 bb = reinterpret_cast<const float4*>(bo)[tid];
  float4 v = {bb.x + xv.x, bb.y + xv.y, bb.z + xv.z, bb.w + xv.w};
#pragma unroll
  for (int z = 0; z < 4; ++z) {
    const ushort4 a = reinterpret_cast<const ushort4*>(p + (size_t)z * 4194304 + (size_t)row * 1024)[tid];
    v.x += bf2f(a.x); v.y += bf2f(a.y); v.z += bf2f(a.z); v.w += bf2f(a.w);
  }
  reinterpret_cast<float4*>(x2 + (size_t)row * 1024)[tid] = v;
  float s = v.x + v.y + v.z + v.w;
  float ss = v.x * v.x + v.y * v.y + v.z * v.z + v.w * v.w;
#pragma unroll
  for (int off = 32; off; off >>= 1) {
    s += __shfl_xor(s, off, 64);
    ss += __shfl_xor(ss, off, 64);
  }
  __shared__ float red[8];
  const int wave = tid >> 6, lane = tid & 63;
  if (lane == 0) { red[wave] = s; red[4 + wave] = ss; }
  __syncthreads();
  const float mu = (red[0] + red[1] + red[2] + red[3]) * (1.f / 1024.f);
  const float ms = (red[4] + red[5] + red[6] + red[7]) * (1.f / 1024.f);
  const float rstd = rsqrtf(ms - mu * mu + 1e-5f);
  const float4 gg = reinterpret_cast<const float4*>(g)[tid];
  const float4 eb = reinterpret_cast<const float4*>(be)[tid];
  bf16_t* o = xn + (size_t)row * 1024 + tid * 4;
  o[0] = f2bf((v.x - mu) * rstd * gg.x + eb.x);
  o[1] = f2bf((v.y - mu) * rstd * gg.y + eb.y);
  o[2] = f2bf((v.z - mu) * rstd * gg.z + eb.z);
  o[3] = f2bf((v.w - mu) * rstd * gg.w + eb.w);
}

// ---------------------------------------------------------------------------
// FFN combine: out = bf(p0)+bf(p1)+bf(p2)+b2+x2
// ---------------------------------------------------------------------------
__global__ __launch_bounds__(256) void ffn_combine(const bf16_t* __restrict__ p0,
                                                   const bf16_t* __restrict__ p2,
                                                   const float* __restrict__ x2,
                                                   const float* __restrict__ b2,
                                                   float* __restrict__ out) {
  const int row = blockIdx.x;
  const int tid = threadIdx.x;
  const ushort4 a0 = reinterpret_cast<const ushort4*>(p0 + (size_t)row * 1024)[tid];
  const ushort4 a1 = reinterpret_cast<const ushort4*>(p0 + 4194304 + (size_t)row * 1024)[tid];
  const ushort4 a2 = reinterpret_cast<const ushort4*>(p2 + (size_t)row * 1024)[tid];
  const float4 xv = reinterpret_cast<const float4*>(x2 + (size_t)row * 1024)[tid];
  const float4 bb = reinterpret_cast<const float4*>(b2)[tid];
  float4 v;
  v.x = bf2f(a0.x) + bf2f(a1.x) + bf2f(a2.x) + bb.x + xv.x;
  v.y = bf2f(a0.y) + bf2f(a1.y) + bf2f(a2.y) + bb.y + xv.y;
  v.z = bf2f(a0.z) + bf2f(a1.z) + bf2f(a2.z) + bb.z + xv.z;
  v.w = bf2f(a0.w) + bf2f(a1.w) + bf2f(a2.w) + bb.w + xv.w;
  reinterpret_cast<float4*>(out + (size_t)row * 1024)[tid] = v;
}

// ---------------------------------------------------------------------------
// attn7: swapped-QK in-register-softmax flash attention (unchanged from R6).
// ---------------------------------------------------------------------------
__global__ __launch_bounds__(256, 2) void attn7(const bf16_t* __restrict__ qb,
                                                const bf16_t* __restrict__ kb,
                                                const bf16_t* __restrict__ vt,
                                                bf16_t* __restrict__ out) {
  const int bh = blockIdx.x;
  const int tid = threadIdx.x, wave = tid >> 6, lane = tid & 63;
  const int l31 = lane & 31, hi = lane >> 5;
  const int q0 = blockIdx.y * 128 + wave * 32;
  const size_t kvb = (size_t)bh * (2048 * 64);

  __shared__ __align__(16) bf16_t Ks[2][2][4096];
  __shared__ __align__(16) bf16_t Vs[2][2][4096];

  short8 qf[4];
#pragma unroll
  for (int st = 0; st < 4; ++st)
    qf[st] = *(const short8*)&qb[kvb + (size_t)(q0 + l31) * 64 + st * 16 + hi * 8];

  int kidx[2][4];
  int vidx[2][2][2];
#pragma unroll
  for (int st = 0; st < 4; ++st) {
    const int R0 = l31, R1 = 32 + l31;
    kidx[0][st] = (R0 * 8 + (((st << 1) | hi) ^ (R0 & 7))) * 8;
    kidx[1][st] = (R1 * 8 + (((st << 1) | hi) ^ (R1 & 7))) * 8;
  }
#pragma unroll
  for (int f = 0; f < 2; ++f)
#pragma unroll
    for (int ks = 0; ks < 2; ++ks) {
      const int R0 = l31, R1 = 32 + l31;
      vidx[0][f][ks] = (R0 * 8 + (((f << 2) | (ks << 1) | hi) ^ (R0 & 7))) * 8;
      vidx[1][f][ks] = (R1 * 8 + (((f << 2) | (ks << 1) | hi) ^ (R1 & 7))) * 8;
    }

  short8 vones;
#pragma unroll
  for (int j = 0; j < 8; ++j) vones[j] = (short)0x3F80;

  f32x16 acc0 = {}, acc1 = {}, lacc = {};
  const f32x16 fz = {};

#define STAGE(DST, T0)                                                                     \
  {                                                                                        \
    _Pragma("unroll") for (int sub = 0; sub < 2; ++sub) {                                  \
      _Pragma("unroll") for (int j = 0; j < 2; ++j) {                                      \
        const int s = wave * 128 + j * 64 + lane;                                          \
        const int r = s >> 3;                                                              \
        const int c = (s & 7) ^ (r & 7);                                                   \
        gload_lds16(kb + kvb + (size_t)((T0) + sub * 64 + r) * 64 + c * 8,                 \
                    &Ks[DST][sub][(size_t)s * 8]);                                         \
        gload_lds16(vt + kvb + (size_t)r * 2048 + (T0) + sub * 64 + c * 8,                 \
                    &Vs[DST][sub][(size_t)s * 8]);                                         \
      }                                                                                    \
    }                                                                                      \
  }

#define QK(BUF, SUB, P0, P1)                                                               \
  {                                                                                        \
    short8 kfa[4], kfb[4];                                                                 \
    _Pragma("unroll") for (int st = 0; st < 4; ++st) {                                     \
      kfa[st] = *(const short8*)&Ks[BUF][SUB][kidx[0][st]];                                \
      kfb[st] = *(const short8*)&Ks[BUF][SUB][kidx[1][st]];                                \
    }                                                                                      \
    __builtin_amdgcn_s_setprio(1);                                                         \
    P0 = __builtin_amdgcn_mfma_f32_32x32x16_bf16(kfa[0], qf[0], fz, 0, 0, 0);              \
    P1 = __builtin_amdgcn_mfma_f32_32x32x16_bf16(kfb[0], qf[0], fz, 0, 0, 0);              \
    _Pragma("unroll") for (int st = 1; st < 4; ++st) {                                     \
      P0 = __builtin_amdgcn_mfma_f32_32x32x16_bf16(kfa[st], qf[st], P0, 0, 0, 0);          \
      P1 = __builtin_amdgcn_mfma_f32_32x32x16_bf16(kfb[st], qf[st], P1, 0, 0, 0);          \
    }                                                                                      \
    __builtin_amdgcn_s_setprio(0);                                                         \
  }

#define SMPV(BUF, SUB, P0, P1)                                                             \
  {                                                                                        \
    _Pragma("unroll") for (int f = 0; f < 2; ++f) {                                        \
      f32x16& p = f ? P1 : P0;                                                             \
      float e[16];                                                                         \
      _Pragma("unroll") for (int r = 0; r < 16; ++r) e[r] = __ocml_native_exp2_f32(p[r]);  \
      unsigned int a0 = cvt_pk_bf16(e[0], e[1]), b0 = cvt_pk_bf16(e[4], e[5]);             \
      unsigned int a1 = cvt_pk_bf16(e[2], e[3]), b1 = cvt_pk_bf16(e[6], e[7]);             \
      unsigned int a2 = cvt_pk_bf16(e[8], e[9]), b2 = cvt_pk_bf16(e[12], e[13]);           \
      unsigned int a3 = cvt_pk_bf16(e[10], e[11]), b3 = cvt_pk_bf16(e[14], e[15]);         \
      pl32swap(a0, b0);                                                                    \
      pl32swap(a1, b1);                                                                    \
      pl32swap(a2, b2);                                                                    \
      pl32swap(a3, b3);                                                                    \
      const u32x4 w0 = {a0, a1, b0, b1};                                                   \
      const u32x4 w1 = {a2, a3, b2, b3};                                                   \
      const short8 pf0 = __builtin_bit_cast(short8, w0);                                   \
      const short8 pf1 = __builtin_bit_cast(short8, w1);                                   \
      const short8 vf00 = *(const short8*)&Vs[BUF][SUB][vidx[0][f][0]];                    \
      const short8 vf10 = *(const short8*)&Vs[BUF][SUB][vidx[1][f][0]];                    \
      const short8 vf01 = *(const short8*)&Vs[BUF][SUB][vidx[0][f][1]];                    \
      const short8 vf11 = *(const short8*)&Vs[BUF][SUB][vidx[1][f][1]];                    \
      __builtin_amdgcn_s_setprio(1);                                                       \
      lacc = __builtin_amdgcn_mfma_f32_32x32x16_bf16(pf0, vones, lacc, 0, 0, 0);           \
      acc0 = __builtin_amdgcn_mfma_f32_32x32x16_bf16(pf0, vf00, acc0, 0, 0, 0);            \
      acc1 = __builtin_amdgcn_mfma_f32_32x32x16_bf16(pf0, vf10, acc1, 0, 0, 0);            \
      lacc = __builtin_amdgcn_mfma_f32_32x32x16_bf16(pf1, vones, lacc, 0, 0, 0);           \
      acc0 = __builtin_amdgcn_mfma_f32_32x32x16_bf16(pf1, vf01, acc0, 0, 0, 0);            \
      acc1 = __builtin_amdgcn_mfma_f32_32x32x16_bf16(pf1, vf11, acc1, 0, 0, 0);            \
      __builtin_amdgcn_s_setprio(0);                                                       \
    }                                                                                      \
  }

#define CITER(BUF, NT0, DOPREF)                                                            \
  {                                                                                        \
    if (DOPREF) {                                                                          \
      STAGE((BUF) ^ 1, NT0);                                                               \
      asm volatile("s_waitcnt vmcnt(8)" ::: "memory");                                     \
    } else {                                                                               \
      asm volatile("s_waitcnt vmcnt(0)" ::: "memory");                                     \
    }                                                                                      \
    __builtin_amdgcn_s_barrier();                                                          \
    asm volatile("" ::: "memory");                                                         \
    f32x16 pa0, pa1, pb0, pb1;                                                             \
    QK(BUF, 0, pa0, pa1);                                                                  \
    QK(BUF, 1, pb0, pb1);                                                                  \
    SMPV(BUF, 0, pa0, pa1);                                                                \
    SMPV(BUF, 1, pb0, pb1);                                                                \
    asm volatile("" ::: "memory");                                                         \
    __builtin_amdgcn_s_barrier();                                                          \
    asm volatile("" ::: "memory");                                                         \
  }

  STAGE(0, 0);

  for (int k = 0; k < 7; ++k) {
    CITER(0, (2 * k + 1) * 128, 1)
    CITER(1, (2 * k + 2) * 128, 1)
  }
  CITER(0, 1920, 1)
  CITER(1, 0, 0)
#undef CITER
#undef SMPV
#undef QK
#undef STAGE

  const int b = bh >> 4, h = bh & 15;
#pragma unroll
  for (int r = 0; r < 16; ++r) {
    const int qrow = (r & 3) + 8 * (r >> 2) + 4 * hi;
    const float rl = 1.f / lacc[r];
    const size_t ro = (size_t)(b * 2048 + q0 + qrow) * 1024 + h * 64;
    out[ro + l31] = f2bf(acc0[r] * rl);
    out[ro + 32 + l31] = f2bf(acc1[r] * rl);
  }
}

// ---------------------------------------------------------------------------
// gemm_ff1_256: 256x256-tile 8-wave 8-phase counted-vmcnt bf16 GEMM for FF1
// (unchanged from R6).
// ---------------------------------------------------------------------------
#define SWZ4(r) (((r) ^ ((r) >> 2)) & 3)
#define HP(SL, H) (dynlds + (size_t)(((SL) * 4 + (H)) * 8192))

#define STAGE8(dst, src, row0, kc0)                                             \
  {                                                                             \
    _Pragma("unroll") for (int j = 0; j < 2; ++j) {                             \
      const int s_ = j * 512 + tid;                                             \
      const int r_ = s_ >> 2;                                                   \
      const int c_ = (s_ & 3) ^ SWZ4(r_);                                       \
      gload_lds16(src + (size_t)((row0) + r_) * 1024 + (kc0) + c_ * 8,          \
                  (dst) + (size_t)s_ * 8);                                      \
    }                                                                           \
  }

#define PHASE(SL, KH, MH, STG, VMW)                                             \
  {                                                                             \
    STG;                                                                        \
    short8 af_[4];                                                              \
    _Pragma("unroll") for (int q4 = 0; q4 < 4; ++q4)                            \
      af_[q4] = *(const short8*)(HP(SL, KH) + aidx[(MH) * 4 + q4]);             \
    if ((MH) == 0) {                                                            \
      _Pragma("unroll") for (int ni = 0; ni < 4; ++ni)                          \
        bfr[ni] = *(const short8*)(HP(SL, 2 + (KH)) + bidx[ni]);                \
    }                                                                           \
    VMW;                                                                        \
    asm volatile("" ::: "memory");                                              \
    __builtin_amdgcn_s_barrier();                                               \
    asm volatile("" ::: "memory");                                              \
    __builtin_amdgcn_s_setprio(1);                                              \
    _Pragma("unroll") for (int q4 = 0; q4 < 4; ++q4)                            \
      _Pragma("unroll") for (int ni = 0; ni < 4; ++ni)                          \
        acc[(MH) * 4 + q4][ni] = __builtin_amdgcn_mfma_f32_16x16x32_bf16(       \
            af_[q4], bfr[ni], acc[(MH) * 4 + q4][ni], 0, 0, 0);                 \
    __builtin_amdgcn_s_setprio(0);                                              \
    asm volatile("" ::: "memory");                                              \
    __builtin_amdgcn_s_barrier();                                               \
    asm volatile("" ::: "memory");                                              \
  }

#define KTILE(SL, KT, VM2, VM4)                                                 \
  PHASE(SL, 0, 0,                                                               \
        if ((KT) + 1 < 16) STAGE8(HP((SL) ^ 1, 2), BT, n0, ((KT) + 1) * 64),    \
        (void)0)                                                                \
  PHASE(SL, 0, 1,                                                               \
        if ((KT) + 1 < 16) STAGE8(HP((SL) ^ 1, 1), A, m0, ((KT) + 1) * 64 + 32),\
        asm volatile("s_waitcnt vmcnt(" #VM2 ")" ::: "memory"))                 \
  PHASE(SL, 1, 0,                                                               \
        if ((KT) + 1 < 16) STAGE8(HP((SL) ^ 1, 3), BT, n0, ((KT) + 1) * 64 + 32),\
        (void)0)                                                                \
  PHASE(SL, 1, 1,                                                               \
        if ((KT) + 2 < 16) STAGE8(HP(SL, 0), A, m0, ((KT) + 2) * 64),           \
        asm volatile("s_waitcnt vmcnt(" #VM4 ")" ::: "memory"))

__global__ __launch_bounds__(512, 2) void gemm_ff1_256(
    const bf16_t* __restrict__ A, const bf16_t* __restrict__ BT,
    const float* __restrict__ bias, bf16_t* __restrict__ ob) {
  extern __shared__ bf16_t dynlds[];
  const int tid = threadIdx.x;
  const int wave = tid >> 6, lane = tid & 63;
  const int row16 = lane & 15, quad = lane >> 4;
  const int wr = wave >> 2, wc = wave & 3;
  const int m0 = blockIdx.x * 256, n0 = blockIdx.y * 256;

  int aidx[8], bidx[4];
#pragma unroll
  for (int mi = 0; mi < 8; ++mi) {
    const int R = wr * 128 + mi * 16 + row16;
    aidx[mi] = R * 32 + (quad ^ SWZ4(R)) * 8;
  }
#pragma unroll
  for (int ni = 0; ni < 4; ++ni) {
    const int R = wc * 64 + ni * 16 + row16;
    bidx[ni] = R * 32 + (quad ^ SWZ4(R)) * 8;
  }

  f32x4 acc[8][4];
#pragma unroll
  for (int i = 0; i < 8; ++i)
#pragma unroll
    for (int j = 0; j < 4; ++j) acc[i][j] = (f32x4){0.f, 0.f, 0.f, 0.f};
  short8 bfr[4];

  STAGE8(HP(0, 0), A, m0, 0);
  STAGE8(HP(0, 2), BT, n0, 0);
  STAGE8(HP(0, 1), A, m0, 32);
  STAGE8(HP(0, 3), BT, n0, 32);
  STAGE8(HP(1, 0), A, m0, 64);
  __syncthreads();

  for (int kt2 = 0; kt2 < 7; ++kt2) {
    const int kt = 2 * kt2;
    KTILE(0, kt, 6, 4)
    KTILE(1, kt + 1, 6, 4)
  }
  KTILE(0, 14, 6, 4)
  KTILE(1, 15, 0, 0)

  __syncthreads();
  bf16_t* ct = dynlds;  // [128][264]
  float bsv[4];
#pragma unroll
  for (int ni = 0; ni < 4; ++ni) bsv[ni] = bias[n0 + wc * 64 + ni * 16 + row16];
#pragma unroll
  for (int mh = 0; mh < 2; ++mh) {
    if (wr == mh) {
#pragma unroll
      for (int mi = 0; mi < 8; ++mi)
#pragma unroll
        for (int ni = 0; ni < 4; ++ni)
#pragma unroll
          for (int r = 0; r < 4; ++r) {
            const float c = fmaxf(acc[mi][ni][r] + bsv[ni], 0.f);
            ct[(size_t)(mi * 16 + quad * 4 + r) * 264 + wc * 64 + ni * 16 + row16] = f2bf(c);
          }
    }
    __syncthreads();
#pragma unroll
    for (int it = 0; it < 8; ++it) {
      const int u = it * 512 + tid;
      const int lr = u >> 5, lcq = u & 31;
      const uint4 v = *(const uint4*)&ct[(size_t)lr * 264 + lcq * 8];
      *(uint4*)&ob[(size_t)(m0 + mh * 128 + lr) * 4096 + n0 + lcq * 8] = v;
    }
    __syncthreads();
  }
}

// ---------------------------------------------------------------------------
// bf16 MFMA GEMM, C = A[M][K] @ BT[N][K]^T (m97-class; QKV/Wo/FF2).
// MODE_QKV epilogue fuses RoPE (Q scaled by 0.125*log2e) using a bf16-packed
// cos/sin table STAGED THROUGH LDS (no latency-exposed global tail reads),
// and writes V transposed directly to vt[b,h,d,s].
// ---------------------------------------------------------------------------
enum { MODE_QKV = 0, MODE_FF1 = 1, MODE_PART = 2 };

template <int MODE>
__global__ __launch_bounds__(256) void gemm_bt(
    const bf16_t* __restrict__ A, const bf16_t* __restrict__ BT,
    int M, int N, int K, int kspan,
    const float* __restrict__ bias0, const float* __restrict__ bias1,
    const float* __restrict__ bias2, const unsigned int* __restrict__ ropetbl,
    bf16_t* __restrict__ ob0, bf16_t* __restrict__ ob1, bf16_t* __restrict__ ob2) {
  // QKV mode: +16 KB LDS for the staged rope-table rows [128][32] u32.
  __shared__ __align__(16) char smem[MODE == MODE_QKV ? 51200 : 34816];
  bf16_t* As = (bf16_t*)smem;
  bf16_t* Bs = (bf16_t*)(smem + 16384);
  const int tid = threadIdx.x;
  const int wave = tid >> 6, lane = tid & 63;
  const int row16 = lane & 15, quad = lane >> 4;
  const int m0 = blockIdx.x * 128, n0 = blockIdx.y * 128;
  const int wm = (wave & 1) << 6, wn = (wave >> 1) << 6;

  f32x4 acc[4][4];
#pragma unroll
  for (int i = 0; i < 4; ++i)
#pragma unroll
    for (int j = 0; j < 4; ++j) acc[i][j] = (f32x4){0.f, 0.f, 0.f, 0.f};

  const int kb = blockIdx.z * kspan;
  const int kend = (kb + kspan < K) ? kb + kspan : K;

  for (int k0 = kb; k0 < kend; k0 += 64) {
#pragma unroll
    for (int j = 0; j < 4; ++j) {
      const int s = j * 256 + tid;
      const int r = s >> 3;
      const int cg = ((s & 7) ^ (r & 7)) << 3;
      gload_lds16(A + (size_t)(m0 + r) * K + k0 + cg, As + (size_t)s * 8);
      gload_lds16(BT + (size_t)(n0 + r) * K + k0 + cg, Bs + (size_t)s * 8);
    }
    __syncthreads();
    const int sw = row16 & 7;
#pragma unroll
    for (int kk = 0; kk < 2; ++kk) {
      short8 af[4], bfr[4];
#pragma unroll
      for (int mi = 0; mi < 4; ++mi)
        af[mi] = *(const short8*)&As[(size_t)(wm + mi * 16 + row16) * 64 + (((kk << 2) | quad) ^ sw) * 8];
#pragma unroll
      for (int ni = 0; ni < 4; ++ni)
        bfr[ni] = *(const short8*)&Bs[(size_t)(wn + ni * 16 + row16) * 64 + (((kk << 2) | quad) ^ sw) * 8];
#pragma unroll
      for (int mi = 0; mi < 4; ++mi)
#pragma unroll
        for (int ni = 0; ni < 4; ++ni)
          acc[mi][ni] =
              __builtin_amdgcn_mfma_f32_16x16x32_bf16(af[mi], bfr[ni], acc[mi][ni], 0, 0, 0);
    }
    __syncthreads();
  }

  // QKV Q/K blocks: stage the 128 packed rope rows (16 KB) into LDS now;
  // latency hides under the acc->ct VALU phase + the barrier's vmcnt drain.
  if (MODE == MODE_QKV && n0 < 2048) {
    const int sb0 = m0 & 2047;
    char* tl = smem + 34816;
#pragma unroll
    for (int j = 0; j < 4; ++j) {
      const int c = j * 256 + tid;  // 16B chunk id, 1024 total
      gload_lds16(ropetbl + (size_t)sb0 * 32 + c * 4, tl + (size_t)c * 16);
    }
  }

  bf16_t* ct = (bf16_t*)smem;  // [128][136]
#pragma unroll
  for (int mi = 0; mi < 4; ++mi)
#pragma unroll
    for (int ni = 0; ni < 4; ++ni) {
      const int gn = n0 + wn + ni * 16 + row16;
      float bsv = 0.f;
      if (MODE == MODE_QKV)
        bsv = (gn < 1024) ? bias0[gn] : (gn < 2048) ? bias1[gn - 1024] : bias2[gn - 2048];
      else if (MODE == MODE_FF1)
        bsv = bias0[gn];
#pragma unroll
      for (int r = 0; r < 4; ++r) {
        float c = acc[mi][ni][r] + bsv;
        if (MODE == MODE_FF1) c = fmaxf(c, 0.f);
        ct[(size_t)(wm + mi * 16 + quad * 4 + r) * 136 + wn + ni * 16 + row16] = f2bf(c);
      }
    }
  __syncthreads();  // drains the table gload_lds (vmcnt 0 before barrier)

  if (MODE == MODE_QKV && n0 >= 2048) {
    // V: transposed store to vt[b,h,d,2048]
    const int b = m0 >> 11, sb = m0 & 2047;
#pragma unroll
    for (int it = 0; it < 8; ++it) {
      const int u = it * 256 + tid;
      const int sg = u & 15, dcol = u >> 4;  // dcol in [0,128)
      const int nnv = (n0 - 2048) + dcol;
      const int h = nnv >> 6, dd = nnv & 63;
      unsigned short eb[8];
#pragma unroll
      for (int k = 0; k < 8; ++k) {
        const int kk = (k + sg) & 7;  // stagger: breaks LDS bank conflicts
        eb[kk] = ct[(size_t)(sg * 8 + kk) * 136 + dcol];
      }
      uint4 o;
      o.x = (unsigned)eb[0] | ((unsigned)eb[1] << 16);
      o.y = (unsigned)eb[2] | ((unsigned)eb[3] << 16);
      o.z = (unsigned)eb[4] | ((unsigned)eb[5] << 16);
      o.w = (unsigned)eb[6] | ((unsigned)eb[7] << 16);
      *(uint4*)&ob2[(((size_t)b * 16 + h) * 64 + dd) * 2048 + sb + sg * 8] = o;
    }
    return;
  }

  const unsigned int* tl32 = (const unsigned int*)(smem + 34816);
  const int lr0 = tid >> 4, lc = tid & 15;
#pragma unroll
  for (int i = 0; i < 8; ++i) {
    const int lr = i * 16 + lr0;
    const uint4 v = *(const uint4*)&ct[(size_t)lr * 136 + lc * 8];
    const int gm = m0 + lr;
    if (MODE == MODE_QKV) {
      // Q or K: fused RoPE on adjacent pairs, then [b,h,s,d] store.
      const int nn = (n0 & 1023) + lc * 8;
      const int h = nn >> 6, d0 = nn & 63;
      const int b = gm >> 11, s = gm & 2047;
      const float scale = (n0 < 1024) ? 0.18033688f : 1.0f;  // 0.125*log2(e)
      // packed table from LDS: row lr, pairs d0/2 .. d0/2+3 (16B aligned)
      const u32x4 tb = *(const u32x4*)&tl32[lr * 32 + (d0 >> 1)];
      const float c0 = bf2f((unsigned short)(tb[0] & 0xffff)), n0r = bf2f((unsigned short)(tb[0] >> 16));
      const float c1 = bf2f((unsigned short)(tb[1] & 0xffff)), n1r = bf2f((unsigned short)(tb[1] >> 16));
      const float c2 = bf2f((unsigned short)(tb[2] & 0xffff)), n2r = bf2f((unsigned short)(tb[2] >> 16));
      const float c3 = bf2f((unsigned short)(tb[3] & 0xffff)), n3r = bf2f((unsigned short)(tb[3] >> 16));
      const float e0 = bf2f(v.x & 0xffff), e1 = bf2f(v.x >> 16);
      const float e2 = bf2f(v.y & 0xffff), e3 = bf2f(v.y >> 16);
      const float e4 = bf2f(v.z & 0xffff), e5 = bf2f(v.z >> 16);
      const float e6 = bf2f(v.w & 0xffff), e7 = bf2f(v.w >> 16);
      uint4 o;
      o.x = (unsigned)f2bf((e0 * c0 - e1 * n0r) * scale) |
            ((unsigned)f2bf((e0 * n0r + e1 * c0) * scale) << 16);
      o.y = (unsigned)f2bf((e2 * c1 - e3 * n1r) * scale) |
            ((unsigned)f2bf((e2 * n1r + e3 * c1) * scale) << 16);
      o.z = (unsigned)f2bf((e4 * c2 - e5 * n2r) * scale) |
            ((unsigned)f2bf((e4 * n2r + e5 * c2) * scale) << 16);
      o.w = (unsigned)f2bf((e6 * c3 - e7 * n3r) * scale) |
            ((unsigned)f2bf((e6 * n3r + e7 * c3) * scale) << 16);
      bf16_t* dst = (n0 < 1024) ? ob0 : ob1;
      *(uint4*)&dst[(((size_t)b * 16 + h) * 2048 + s) * 64 + d0] = o;
    } else if (MODE == MODE_FF1) {
      *(uint4*)&ob0[(size_t)gm * N + n0 + lc * 8] = v;
    } else {
      bf16_t* dst = (blockIdx.z == 2) ? ob1 : ob0 + (size_t)blockIdx.z * 4194304;
      *(uint4*)&dst[(size_t)gm * N + n0 + lc * 8] = v;
    }
  }
}

// ---------------------------------------------------------------------------
extern "C" void kernel_launch(void* const* d_in, const int* in_sizes, int n_in,
                              void* d_out, int out_size, void* d_ws, size_t ws_size,
                              hipStream_t stream) {
  const float* x = (const float*)d_in[0];
  const float* Wq = (const float*)d_in[1];
  const float* bq = (const float*)d_in[2];
  const float* Wk = (const float*)d_in[3];
  const float* bk = (const float*)d_in[4];
  const float* Wv = (const float*)d_in[5];
  const float* bv = (const float*)d_in[6];
  const float* Wo = (const float*)d_in[7];
  const float* bo = (const float*)d_in[8];
  const float* W1 = (const float*)d_in[9];
  const float* b1 = (const float*)d_in[10];
  const float* W2 = (const float*)d_in[11];
  const float* b2 = (const float*)d_in[12];
  const float* g1 = (const float*)d_in[13];
  const float* be1 = (const float*)d_in[14];
  const float* g2 = (const float*)d_in[15];
  const float* be2 = (const float*)d_in[16];
  float* out = (float*)d_out;

  char* ws = (char*)d_ws;
  size_t off = 0;
  auto alloc = [&](size_t bytes) {
    void* p = ws + off;
    off += (bytes + 255) & ~(size_t)255;
    return p;
  };
  bf16_t* WqkvT = (bf16_t*)alloc(3072ULL * 1024 * 2);  // [0,6MB)
  bf16_t* WoT = (bf16_t*)alloc(1024ULL * 1024 * 2);    // [6,8)
  bf16_t* W1T = (bf16_t*)alloc(4096ULL * 1024 * 2);    // [8,16)
  bf16_t* W2T = (bf16_t*)alloc(1024ULL * 4096 * 2);    // [16,24)
  bf16_t* xnb = (bf16_t*)alloc(4096ULL * 1024 * 2);    // [24,32)
  bf16_t* qb = (bf16_t*)alloc(4194304ULL * 2);         // [32,40)
  bf16_t* kb = (bf16_t*)alloc(4194304ULL * 2);         // [40,48)
  bf16_t* vraw = (bf16_t*)alloc(4194304ULL * 2);       // [48,56) now: rope table (dead after QKV)
  bf16_t* vt = (bf16_t*)alloc(4194304ULL * 2);         // [56,64)
  bf16_t* h1 = qb;       // FF1 out [4096][4096] bf16 over [32,64)
  bf16_t* x2p = qb;      // X2 bf16 partials (4 x 8MB) over [32,64), pre-FF1
  bf16_t* ffp = WqkvT;   // FF2 partials 0,1 over dead weights [0,16)
  float* x2 = (float*)alloc(16777216ULL);              // [64,80)
  unsigned int* ropetbl = (unsigned int*)vraw;         // 256KB within [48,56)

  static bool attrset = false;
  if (!attrset) {
    hipFuncSetAttribute((const void*)gemm_ff1_256,
                        hipFuncAttributeMaxDynamicSharedMemorySize, 131072);
    attrset = true;
  }

  prep_kernel<<<16640, 256, 0, stream>>>(Wq, Wk, Wv, Wo, W1, W2, x, g1, be1,
                                         WqkvT, W1T, W2T, xnb, ropetbl);

  // QKV with fused RoPE (Q,K) + transposed V store (vt) in the epilogue.
  gemm_bt<MODE_QKV><<<dim3(32, 24, 1), 256, 0, stream>>>(xnb, WqkvT, 4096, 3072, 1024, 1024,
                                                         bq, bk, bv, ropetbl, qb, kb, vt);

  attn7<<<dim3(32, 16), 256, 0, stream>>>(qb, kb, vt, xnb);

  // X2 = attn_out @ Wo, split-K=4 (kspan 256)
  gemm_bt<MODE_PART><<<dim3(32, 8, 4), 256, 0, stream>>>(xnb, WoT, 4096, 1024, 1024, 256,
                                                         nullptr, nullptr, nullptr, nullptr,
                                                         x2p, x2p + 2 * 4194304, nullptr);

  ln2_combine<<<4096, 256, 0, stream>>>(x2p, x, bo, g2, be2, x2, xnb);

  // FF1 via 8-phase 256^2 kernel
  gemm_ff1_256<<<dim3(16, 16), 512, 131072, stream>>>(xnb, W1T, b1, h1);

  // FF2 = h1 @ W2, split-K=3 (1408/1408/1280)
  gemm_bt<MODE_PART><<<dim3(32, 8, 3), 256, 0, stream>>>(h1, W2T, 4096, 1024, 4096, 1408,
                                                         nullptr, nullptr, nullptr, nullptr,
                                                         ffp, xnb, nullptr);

  ffn_combine<<<4096, 256, 0, stream>>>(ffp, xnb, x2, b2, out);
}